// Round 12
// baseline (128.918 us; speedup 1.0000x reference)
//
#include <hip/hip_runtime.h>

// Problem constants: B=8, S=2048, D=512, G=2, V=320, CV=128
#define M_ROWS 16384   // B*S
#define K_DIM  512
#define N_COLS 640     // G*V
#define V_CODES 320
#define CV_DIM 128

typedef _Float16 half8 __attribute__((ext_vector_type(8)));
typedef _Float16 half4v __attribute__((ext_vector_type(4)));
typedef float floatx4 __attribute__((ext_vector_type(4)));

__device__ inline void gll16(const void* g, void* l) {
    __builtin_amdgcn_global_load_lds(
        (const __attribute__((address_space(1))) void*)g,
        (__attribute__((address_space(3))) void*)l, 16, 0, 0);
}

// ---------------------------------------------------------------------------
// Kernel 0: prepW — LDS-tiled transpose W (512,640) f32 -> Wt (640,512) f16;
// block 320 zeroes the global marginal.
// ---------------------------------------------------------------------------
__global__ __launch_bounds__(256)
void prepW(const float* __restrict__ W, _Float16* __restrict__ Wt,
           float* __restrict__ marginal) {
    __shared__ float tile[32][33];
    const int b = blockIdx.x, t = threadIdx.x;
    if (b == 320) {
        for (int i = t; i < 640; i += 256) marginal[i] = 0.f;
        return;
    }
    const int n0 = (b % 20) * 32, k0 = (b / 20) * 32;
    {
        const int kk = t >> 3, nn4 = (t & 7) << 2;
        const float4 w = *(const float4*)(W + (size_t)(k0 + kk) * 640 + n0 + nn4);
        tile[kk][nn4 + 0] = w.x; tile[kk][nn4 + 1] = w.y;
        tile[kk][nn4 + 2] = w.z; tile[kk][nn4 + 3] = w.w;
    }
    __syncthreads();
    {
        const int nn = t >> 3, kk4 = (t & 7) << 2;
        half4v h = {(_Float16)tile[kk4 + 0][nn], (_Float16)tile[kk4 + 1][nn],
                    (_Float16)tile[kk4 + 2][nn], (_Float16)tile[kk4 + 3][nn]};
        *(half4v*)(Wt + (size_t)(n0 + nn) * 512 + k0 + kk4) = h;
    }
}

// ---------------------------------------------------------------------------
// Fused kernel (round-8 geometry + LDS-staged gumbel epilogue):
// grid (256 bm, 2 g), 256 threads = 4 waves; wave mi owns 16 rows x all 320
// cols (acc[20]). K-loop: dbuf gll16 staging, BK=32, one barrier/step
// (round-8-proven). Epilogue: gumbel tile staged to LDS via gll16 in TWO
// 40 KB passes (rows p*32..p*32+31) into the dead staging union — bulk async,
// zero register pressure — then waves {2p,2p+1} do argmax/softmax with
// LDS-resident gumbels, cv gather + out, per-pass marginal flush to smarg.
// ---------------------------------------------------------------------------
union SMemG {
    struct { _Float16 Bs[2][320 * 32]; _Float16 As[2][64 * 32]; } g;  // 48 KB
    float gumL[32 * 320];                                             // 40 KB
};

__global__ __launch_bounds__(256, 3)
void fused(const float* __restrict__ A, const _Float16* __restrict__ Bt,
           const float* __restrict__ bias, const float* __restrict__ gum,
           const float* __restrict__ cv, float* __restrict__ out,
           float* __restrict__ marginal) {
    __shared__ SMemG sm;
    __shared__ float smarg[320];
    const int t = threadIdx.x;
    const int wave = t >> 6, lane = t & 63;
    const int bm = blockIdx.x, g = blockIdx.y;
    const int mi = wave;
    const int c = lane & 15, kq = lane >> 4;

    for (int i = t; i < 320; i += 256) smarg[i] = 0.f;

    floatx4 acc[20];
#pragma unroll
    for (int nt = 0; nt < 20; ++nt) acc[nt] = (floatx4){0.f, 0.f, 0.f, 0.f};

    // A staging map (round-8-proven): row am, 16B chunk ad, swizzle ^(am&3)
    const int am = t >> 2, ad = t & 3;
    const int a_wr = am * 64 + ((ad ^ (am & 3)) << 4);
    const float* Aptr = A + (size_t)(bm * 64 + am) * 512 + ad * 8;

    const _Float16* Bg = Bt + (size_t)g * V_CODES * K_DIM;

    auto STAGE = [&](int buf, int k0) {
        const float4 av0 = *(const float4*)(Aptr + k0);
        const float4 av1 = *(const float4*)(Aptr + k0 + 4);
#pragma unroll
        for (int s = 0; s < 5; ++s) {
            const int q = t + 256 * s;               // 0..1279
            const int n = q >> 2, j = q & 3;         // row 0..319, chunk 0..3
            gll16(Bg + (size_t)n * 512 + k0 + ((j ^ (n & 3)) << 3),
                  (char*)(&sm.g.Bs[buf][0]) + q * 16);
        }
        const half8 h = {(_Float16)av0.x, (_Float16)av0.y, (_Float16)av0.z,
                         (_Float16)av0.w, (_Float16)av1.x, (_Float16)av1.y,
                         (_Float16)av1.z, (_Float16)av1.w};
        *(half8*)((char*)(&sm.g.As[buf][0]) + a_wr) = h;
    };

    STAGE(0, 0);
    __syncthreads();

    for (int kt = 0; kt < 16; ++kt) {
        const int cur = kt & 1;
        if (kt < 15) STAGE(cur ^ 1, (kt + 1) * 32);
        const int ra = mi * 16 + c;
        const half8 af = *(const half8*)((const char*)(&sm.g.As[cur][0]) +
                          ra * 64 + ((kq ^ (ra & 3)) << 4));
#pragma unroll
        for (int nt = 0; nt < 20; ++nt) {
            const int rb = nt * 16 + c;
            const half8 bf = *(const half8*)((const char*)(&sm.g.Bs[cur][0]) +
                              rb * 64 + ((kq ^ (rb & 3)) << 4));
            acc[nt] = __builtin_amdgcn_mfma_f32_16x16x32_f16(af, bf, acc[nt], 0, 0, 0);
        }
        __syncthreads();   // final barrier also fences the union overwrite below
    }

    // ---- epilogue: two gumbel-LDS passes ----
    for (int p = 0; p < 2; ++p) {
        // bulk-async stage: rows [p*32, p*32+32) of this group's gumbels, f32
#pragma unroll
        for (int s = 0; s < 10; ++s) {
            const int q = t + 256 * s;               // 0..2559 16B chunks
            const int rip = q / 80;                  // row-in-pass 0..31
            const int cir = q % 80;                  // 16B chunk within row
            gll16(gum + ((size_t)(bm * 64 + p * 32 + rip) * 2 + g) * V_CODES
                      + cir * 4,
                  (char*)sm.gumL + q * 16);
        }
        __syncthreads();   // drain vmcnt; gumbels resident

        if ((mi >> 1) == p) {
            const int rbase = (mi & 1) * 16;         // row-in-pass base
            float bcol[20];
#pragma unroll
            for (int nt = 0; nt < 20; ++nt)
                bcol[nt] = bias[g * V_CODES + nt * 16 + c];
            float mcon[20];
#pragma unroll
            for (int nt = 0; nt < 20; ++nt) mcon[nt] = 0.f;

#pragma unroll
            for (int rg = 0; rg < 4; ++rg) {
                const int rip = rbase + kq * 4 + rg;     // row in pass (per-lane)
                float lg[20];
#pragma unroll
                for (int nt = 0; nt < 20; ++nt) lg[nt] = acc[nt][rg] + bcol[nt];
                // per-lane argmax of noisy logits (lowest-index tie)
                float best = -1e30f; int bidx = 0;
#pragma unroll
                for (int nt = 0; nt < 20; ++nt) {
                    const float nz = lg[nt] + sm.gumL[rip * 320 + nt * 16 + c];
                    const int v = nt * 16 + c;
                    if (nz > best) { best = nz; bidx = v; }
                }
                // 16-lane all-reduce argmax (xor 1..8 stays in quarter-wave)
#pragma unroll
                for (int mask = 1; mask <= 8; mask <<= 1) {
                    const float ob = __shfl_xor(best, mask);
                    const int   oi = __shfl_xor(bidx, mask);
                    if (ob > best || (ob == best && oi < bidx)) { best = ob; bidx = oi; }
                }
                // noise-free softmax (no max-sub: logits O(+-6), f32-exact)
                float s = 0.f;
#pragma unroll
                for (int nt = 0; nt < 20; ++nt) { lg[nt] = __expf(lg[nt]); s += lg[nt]; }
#pragma unroll
                for (int mask = 1; mask <= 8; mask <<= 1) s += __shfl_xor(s, mask);
                const float inv = 1.f / s;
#pragma unroll
                for (int nt = 0; nt < 20; ++nt) mcon[nt] += lg[nt] * inv;
                // codevector gather + straight-through output
                const int ntok = bm * 64 + mi * 16 + kq * 4 + rg;
                const float4* cvp = (const float4*)(cv +
                    ((size_t)g * V_CODES + bidx) * CV_DIM) + c * 2;
                const float4 v0 = cvp[0], v1 = cvp[1];
                float4* op = (float4*)(out + (size_t)ntok * 256 + g * CV_DIM) + c * 2;
                op[0] = v0; op[1] = v1;
            }

            // per-pass marginal flush: reduce quarter-wave groups -> smarg
#pragma unroll
            for (int nt = 0; nt < 20; ++nt) {
                mcon[nt] += __shfl_xor(mcon[nt], 16);
                mcon[nt] += __shfl_xor(mcon[nt], 32);
            }
            if (lane < 16) {
#pragma unroll
                for (int nt = 0; nt < 20; ++nt)
                    atomicAdd(&smarg[nt * 16 + c], mcon[nt]);
            }
        }
        __syncthreads();   // pass-p readers done before pass-(p+1) overwrite
    }

    // global marginal flush
    for (int i = t; i < 320; i += 256)
        atomicAdd(marginal + g * V_CODES + i, smarg[i]);
}

// ---------------------------------------------------------------------------
// Kernel 2: finalize perplexity from the global marginal (640 floats).
// ---------------------------------------------------------------------------
__global__ __launch_bounds__(640)
void finalize(const float* __restrict__ marginal, float* __restrict__ perp_out) {
    __shared__ float terms[640];
    __shared__ float gsum[2];
    const int t = threadIdx.x;

    const float m = marginal[t] * (1.0f / (float)M_ROWS);
    terms[t] = -m * __logf(m + 1e-7f);
    __syncthreads();

    if (t < 128) {
        const int g = t >> 6, lane = t & 63;
        float e = 0.f;
#pragma unroll
        for (int j = 0; j < 5; ++j) e += terms[g * V_CODES + lane + 64 * j];
#pragma unroll
        for (int off = 32; off; off >>= 1) e += __shfl_down(e, off);
        if (lane == 0) gsum[g] = e;
    }
    __syncthreads();
    if (t == 0) perp_out[0] = __expf(gsum[0]) + __expf(gsum[1]);
}

// ---------------------------------------------------------------------------
extern "C" void kernel_launch(void* const* d_in, const int* in_sizes, int n_in,
                              void* d_out, int out_size, void* d_ws, size_t ws_size,
                              hipStream_t stream) {
    (void)in_sizes; (void)n_in; (void)out_size; (void)ws_size;
    const float* hs = (const float*)d_in[0];   // (8,2048,512) f32
    const float* W  = (const float*)d_in[1];   // (512,640)    f32
    const float* bi = (const float*)d_in[2];   // (640,)       f32
    const float* cv = (const float*)d_in[3];   // (1,640,128)  f32
    const float* gu = (const float*)d_in[4];   // (32768,320)  f32
    float* out = (float*)d_out;                // 16384*256 + 1

    // ws: Wt f16 (640 KB) + marginal (640 f32)
    _Float16* Wt       = (_Float16*)d_ws;
    float*    marginal = (float*)(Wt + (size_t)N_COLS * K_DIM);

    prepW<<<321, 256, 0, stream>>>(W, Wt, marginal);
    fused<<<dim3(256, 2), 256, 0, stream>>>(hs, Wt, bi, gu, cv, out, marginal);
    finalize<<<1, 640, 0, stream>>>(marginal, out + (size_t)M_ROWS * 256);
}

// Round 13
// 57.233 us; speedup vs baseline: 2.2525x; 2.2525x over previous
//
#include <hip/hip_runtime.h>

// Problem constants: B=8, S=2048, D=512, G=2, V=320, CV=128
#define M_ROWS 16384   // B*S
#define K_DIM  512
#define N_COLS 640     // G*V
#define V_CODES 320
#define CV_DIM 128
#define LSTR 328       // padded f16 logit-row stride in LDS (bank-spread)

typedef _Float16 half8 __attribute__((ext_vector_type(8)));
typedef _Float16 half4v __attribute__((ext_vector_type(4)));
typedef float floatx4 __attribute__((ext_vector_type(4)));

__device__ inline void gll16(const void* g, void* l) {
    __builtin_amdgcn_global_load_lds(
        (const __attribute__((address_space(1))) void*)g,
        (__attribute__((address_space(3))) void*)l, 16, 0, 0);
}

// ---------------------------------------------------------------------------
// Kernel 0: prepW — LDS-tiled transpose W (512,640) f32 -> Wt (640,512) f16;
// block 320 zeroes the global marginal.
// ---------------------------------------------------------------------------
__global__ __launch_bounds__(256)
void prepW(const float* __restrict__ W, _Float16* __restrict__ Wt,
           float* __restrict__ marginal) {
    __shared__ float tile[32][33];
    const int b = blockIdx.x, t = threadIdx.x;
    if (b == 320) {
        for (int i = t; i < 640; i += 256) marginal[i] = 0.f;
        return;
    }
    const int n0 = (b % 20) * 32, k0 = (b / 20) * 32;
    {
        const int kk = t >> 3, nn4 = (t & 7) << 2;
        const float4 w = *(const float4*)(W + (size_t)(k0 + kk) * 640 + n0 + nn4);
        tile[kk][nn4 + 0] = w.x; tile[kk][nn4 + 1] = w.y;
        tile[kk][nn4 + 2] = w.z; tile[kk][nn4 + 3] = w.w;
    }
    __syncthreads();
    {
        const int nn = t >> 3, kk4 = (t & 7) << 2;
        half4v h = {(_Float16)tile[kk4 + 0][nn], (_Float16)tile[kk4 + 1][nn],
                    (_Float16)tile[kk4 + 2][nn], (_Float16)tile[kk4 + 3][nn]};
        *(half4v*)(Wt + (size_t)(n0 + nn) * 512 + k0 + kk4) = h;
    }
}

// ---------------------------------------------------------------------------
// Fused kernel: round-8/11-proven K-loop (BK=32, dbuf gll16, one barrier/step)
// + spill-free staged epilogue:
//   phase 1: acc+bias -> f16 L[64][LSTR] in the dead staging union (acc DIES)
//   phase 2: 4 passes; each stages 16 gumbel rows (20 KB) via gll16 (bulk
//            async, zero reg pressure), then 4 waves x 4 rows full-64-lane
//            reduction (combined argmax+sum butterfly), cv gather + out.
// LDS 70.9 KB -> 2 blocks/CU.
// ---------------------------------------------------------------------------
union SMemG {
    struct { _Float16 Bs[2][320 * 32]; _Float16 As[2][64 * 32]; } g;  // 48 KB
    _Float16 L[64 * LSTR];                                            // 41 KB
};

__global__ __launch_bounds__(256, 2)
void fused(const float* __restrict__ A, const _Float16* __restrict__ Bt,
           const float* __restrict__ bias, const float* __restrict__ gum,
           const float* __restrict__ cv, float* __restrict__ out,
           float* __restrict__ marginal) {
    __shared__ SMemG sm;
    __shared__ float gumL[16 * 320];   // 20 KB, one 16-row pass
    __shared__ float smarg[320];
    const int t = threadIdx.x;
    const int wave = t >> 6, lane = t & 63;
    const int bm = blockIdx.x, g = blockIdx.y;
    const int mi = wave;
    const int c = lane & 15, kq = lane >> 4;

    for (int i = t; i < 320; i += 256) smarg[i] = 0.f;

    floatx4 acc[20];
#pragma unroll
    for (int nt = 0; nt < 20; ++nt) acc[nt] = (floatx4){0.f, 0.f, 0.f, 0.f};

    // A staging map (round-8-proven): row am, 16B chunk ad, swizzle ^(am&3)
    const int am = t >> 2, ad = t & 3;
    const int a_wr = am * 64 + ((ad ^ (am & 3)) << 4);
    const float* Aptr = A + (size_t)(bm * 64 + am) * 512 + ad * 8;

    const _Float16* Bg = Bt + (size_t)g * V_CODES * K_DIM;

    auto STAGE = [&](int buf, int k0) {
        const float4 av0 = *(const float4*)(Aptr + k0);
        const float4 av1 = *(const float4*)(Aptr + k0 + 4);
#pragma unroll
        for (int s = 0; s < 5; ++s) {
            const int q = t + 256 * s;               // 0..1279
            const int n = q >> 2, j = q & 3;         // row 0..319, chunk 0..3
            gll16(Bg + (size_t)n * 512 + k0 + ((j ^ (n & 3)) << 3),
                  (char*)(&sm.g.Bs[buf][0]) + q * 16);
        }
        const half8 h = {(_Float16)av0.x, (_Float16)av0.y, (_Float16)av0.z,
                         (_Float16)av0.w, (_Float16)av1.x, (_Float16)av1.y,
                         (_Float16)av1.z, (_Float16)av1.w};
        *(half8*)((char*)(&sm.g.As[buf][0]) + a_wr) = h;
    };

    STAGE(0, 0);
    __syncthreads();

    for (int kt = 0; kt < 16; ++kt) {
        const int cur = kt & 1;
        if (kt < 15) STAGE(cur ^ 1, (kt + 1) * 32);
        const int ra = mi * 16 + c;
        const half8 af = *(const half8*)((const char*)(&sm.g.As[cur][0]) +
                          ra * 64 + ((kq ^ (ra & 3)) << 4));
#pragma unroll
        for (int nt = 0; nt < 20; ++nt) {
            const int rb = nt * 16 + c;
            const half8 bf = *(const half8*)((const char*)(&sm.g.Bs[cur][0]) +
                              rb * 64 + ((kq ^ (rb & 3)) << 4));
            acc[nt] = __builtin_amdgcn_mfma_f32_16x16x32_f16(af, bf, acc[nt], 0, 0, 0);
        }
        __syncthreads();   // last one also fences the union overwrite below
    }

    // ---- phase 1: acc + bias -> f16 logits in LDS; acc registers DIE here ----
    {
        float bcol[20];
#pragma unroll
        for (int nt = 0; nt < 20; ++nt) bcol[nt] = bias[g * V_CODES + nt * 16 + c];
#pragma unroll
        for (int rg = 0; rg < 4; ++rg) {
            const int row = mi * 16 + kq * 4 + rg;   // per-lane row
#pragma unroll
            for (int nt = 0; nt < 20; ++nt)
                sm.L[row * LSTR + nt * 16 + c] = (_Float16)(acc[nt][rg] + bcol[nt]);
        }
    }

    // ---- phase 2: 4 gumbel passes, 16 rows each; all waves cooperate ----
    float mreg[5];
#pragma unroll
    for (int j = 0; j < 5; ++j) mreg[j] = 0.f;

    for (int p = 0; p < 4; ++p) {
        // bulk-async stage rows [p*16, p*16+16): linear LDS dest (rule #21)
#pragma unroll
        for (int s = 0; s < 5; ++s) {
            const int q = t + 256 * s;               // 0..1279 16B chunks
            const int rip = q / 80;                  // row-in-pass 0..15
            const int cir = q - rip * 80;            // 16B chunk within row
            gll16(gum + ((size_t)(bm * 64 + p * 16 + rip) * 2 + g) * V_CODES
                      + cir * 4,
                  (char*)gumL + q * 16);
        }
        __syncthreads();   // drain: gumbels + (p==0) L-writes visible

        // 4 rows per wave, full-64-lane reduction per row
#pragma unroll
        for (int rr = 0; rr < 4; ++rr) {
            const int ripr = wave * 4 + rr;          // row in pass
            const int row  = p * 16 + ripr;          // block-local row
            float lv[5], ex[5];
            float best = -1e30f; int bidx = 0;
            float ssum = 0.f;
#pragma unroll
            for (int j = 0; j < 5; ++j) {
                const int col = lane + 64 * j;
                lv[j] = (float)sm.L[row * LSTR + col];
                const float nz = lv[j] + gumL[ripr * 320 + col];
                if (nz > best) { best = nz; bidx = col; }
            }
#pragma unroll
            for (int j = 0; j < 5; ++j) { ex[j] = __expf(lv[j]); ssum += ex[j]; }
            // combined 6-level butterfly: argmax (lowest-index tie) + sum
#pragma unroll
            for (int mask = 1; mask <= 32; mask <<= 1) {
                const float ob = __shfl_xor(best, mask);
                const int   oi = __shfl_xor(bidx, mask);
                const float os = __shfl_xor(ssum, mask);
                if (ob > best || (ob == best && oi < bidx)) { best = ob; bidx = oi; }
                ssum += os;
            }
            const float inv = 1.f / ssum;
#pragma unroll
            for (int j = 0; j < 5; ++j) mreg[j] += ex[j] * inv;
            // codevector gather + straight-through output (one-hot row bidx)
            const float2 cvv =
                ((const float2*)(cv + ((size_t)g * V_CODES + bidx) * CV_DIM))[lane];
            ((float2*)(out + (size_t)(bm * 64 + row) * 256 + g * CV_DIM))[lane] = cvv;
        }
        __syncthreads();   // pass readers done before next pass overwrites gumL
    }

    // ---- marginal: wave-private mreg -> LDS atomics -> global atomics ----
#pragma unroll
    for (int j = 0; j < 5; ++j) atomicAdd(&smarg[lane + 64 * j], mreg[j]);
    __syncthreads();
    for (int i = t; i < 320; i += 256)
        atomicAdd(marginal + g * V_CODES + i, smarg[i]);
}

// ---------------------------------------------------------------------------
// Kernel 2: finalize perplexity from the global marginal (640 floats).
// ---------------------------------------------------------------------------
__global__ __launch_bounds__(640)
void finalize(const float* __restrict__ marginal, float* __restrict__ perp_out) {
    __shared__ float terms[640];
    __shared__ float gsum[2];
    const int t = threadIdx.x;

    const float m = marginal[t] * (1.0f / (float)M_ROWS);
    terms[t] = -m * __logf(m + 1e-7f);
    __syncthreads();

    if (t < 128) {
        const int g = t >> 6, lane = t & 63;
        float e = 0.f;
#pragma unroll
        for (int j = 0; j < 5; ++j) e += terms[g * V_CODES + lane + 64 * j];
#pragma unroll
        for (int off = 32; off; off >>= 1) e += __shfl_down(e, off);
        if (lane == 0) gsum[g] = e;
    }
    __syncthreads();
    if (t == 0) perp_out[0] = __expf(gsum[0]) + __expf(gsum[1]);
}

// ---------------------------------------------------------------------------
extern "C" void kernel_launch(void* const* d_in, const int* in_sizes, int n_in,
                              void* d_out, int out_size, void* d_ws, size_t ws_size,
                              hipStream_t stream) {
    (void)in_sizes; (void)n_in; (void)out_size; (void)ws_size;
    const float* hs = (const float*)d_in[0];   // (8,2048,512) f32
    const float* W  = (const float*)d_in[1];   // (512,640)    f32
    const float* bi = (const float*)d_in[2];   // (640,)       f32
    const float* cv = (const float*)d_in[3];   // (1,640,128)  f32
    const float* gu = (const float*)d_in[4];   // (32768,320)  f32
    float* out = (float*)d_out;                // 16384*256 + 1

    // ws: Wt f16 (640 KB) + marginal (640 f32)
    _Float16* Wt       = (_Float16*)d_ws;
    float*    marginal = (float*)(Wt + (size_t)N_COLS * K_DIM);

    prepW<<<321, 256, 0, stream>>>(W, Wt, marginal);
    fused<<<dim3(256, 2), 256, 0, stream>>>(hs, Wt, bi, gu, cv, out, marginal);
    finalize<<<1, 640, 0, stream>>>(marginal, out + (size_t)M_ROWS * 256);
}